// Round 15
// baseline (188.266 us; speedup 1.0000x reference)
//
#include <hip/hip_runtime.h>

#define DIM_W 160
#define DIM_H 192
#define DIM_D 160
#define DIM_B 2

constexpr int TW = 16;      // output tile width
constexpr int TH = 32;      // output tile height (P=2 px/thread in H)
constexpr int CH = 19;      // depth outputs per chunk (27 slices = 3 x 9)
constexpr int NCH = 9;      // ceil(160/19)
constexpr int RH = 40;      // region rows
constexpr int RWDS = 24;    // words per region row (4 + 16 + 4 halo)
constexpr float INV_K = 1.0f / 729.0f;
constexpr double NTOT = 9830400.0;

typedef unsigned int u32;
typedef __attribute__((address_space(1))) const u32 gu32;
typedef __attribute__((address_space(3))) u32 lu32;
typedef _Float16 h2 __attribute__((ext_vector_type(2)));

__global__ void init_kernel(float* out, float* ws) {
    out[0] = 0.0f;
    ws[0] = 0.0f; ws[1] = 0.0f; ws[2] = 0.0f; ws[3] = 0.0f;
}

__device__ __forceinline__ int clampD(int s) {
    return s < 0 ? 0 : (s > DIM_D - 1 ? DIM_D - 1 : s);
}

__device__ __forceinline__ u32 pkf16(float a, float b) {
    return __builtin_bit_cast(u32, __builtin_amdgcn_cvt_pkrtz(a, b));
}

__global__ __launch_bounds__(256, 6)
void lncc3d_kernel(const float* __restrict__ I,
                   const float* __restrict__ T,
                   const float* __restrict__ zsrc,
                   float* __restrict__ out)
{
    // slice region: [buf][field][1024 words] = 40 rows x 24 words (+64-word glds
    // tail pad). Stage-1 phase (4r x 4g) hits quad (6r+g+c) mod 8 exactly
    // twice -> naturally conflict-free b128 reads (verified r9/r11).
    __shared__ __align__(16) float sR[2][2][1024];
    // W-sums f16-packed {pk(I,T),pk(II,TT)}: 8B cells, col rotated (c+r)&15
    __shared__ __align__(16) uint2 wA[RH][16];
    // W-sums IT f32, transposed [w][row], stride 44
    __shared__ __align__(16) float wB[16][44];
    __shared__ float red[4];

    const int tid  = threadIdx.x;
    const int lane = tid & 63;
    const int wid  = tid >> 6;
    const int wo   = tid & 15;
    const int hb   = (tid >> 4) << 1;

    const int bw = blockIdx.x, bh = blockIdx.y, bz = blockIdx.z;
    const int b  = bz / NCH;
    const int c  = bz - b * NCH;
    const int w0 = bw * TW, h0 = bh * TH, d0 = c * CH;
    const int dEnd = min(d0 + CH, DIM_D);

    const int plane = DIM_H * DIM_W;
    const int fld = wid >> 1;             // 0: field I, 1: field T
    const int khi = wid & 1;              // chunks {2,3} vs {0,1}
    const float* Fb = ((wid & 2) ? T : I) + (size_t)b * DIM_D * plane;
    (void)fld;

    // glds mapping (r11, refcheck'd): 4 chunks/field of 1024B;
    // 16B-slot s16 -> (row = s16/6, q = s16%6)
    int boff[2], ldof[2];
#pragma unroll
    for (int i = 0; i < 2; ++i) {
        const int ck  = (khi << 1) | i;
        const int s16 = ck * 64 + lane;
        const int row = s16 / 6;
        const int q   = s16 - row * 6;
        const int gh  = h0 - 4 + row;
        const int gw  = w0 - 4 + (q << 2);
        ldof[i] = ck << 8;   // words
        boff[i] = (row < RH && gh >= 0 && gh < DIM_H && gw >= 0 && gw <= DIM_W - 4)
                  ? (gh * DIM_W + gw) : -1;
    }

    auto issue = [&](int sc, int buf) {
        const float* Fs = Fb + (size_t)sc * plane;
#pragma unroll
        for (int i = 0; i < 2; ++i) {
            const float* gp = (boff[i] >= 0) ? (Fs + boff[i]) : zsrc;
            __builtin_amdgcn_global_load_lds((gu32*)gp,
                (lu32*)&sR[buf][(wid & 2) >> 1][ldof[i]], 16, 0, 0);
        }
    };

    // D-rings packed: rgA = {I,T} h2, rgB = {II,TT} h2, rgC = IT f32
    const h2 HZ = __builtin_bit_cast(h2, (u32)0);
    h2 rgA[2][9], rgB[2][9];
    float rgC[2][9];
    float rnI[2], rnT[2], rnII[2], rnTT[2], rnIT[2];
#pragma unroll
    for (int p = 0; p < 2; ++p) {
        rnI[p] = rnT[p] = rnII[p] = rnTT[p] = rnIT[p] = 0.0f;
#pragma unroll
        for (int q = 0; q < 9; ++q) {
            rgA[p][q] = HZ; rgB[p][q] = HZ; rgC[p][q] = 0.0f;
        }
    }
    float acc = 0.0f;

    const int sStart = d0 - 4;
    int cur = 0;

    // ---- prologue: stage sStart -> buf0, sStart+1 -> buf1 ----
    issue(clampD(sStart), 0);
    issue(clampD(sStart + 1), 1);
    asm volatile("s_waitcnt vmcnt(2)" ::: "memory");
    __builtin_amdgcn_s_barrier();

    for (int t = 0; t < 3; ++t) {
        const int t9 = t * 9;
#pragma unroll
        for (int j = 0; j < 9; ++j) {
            const int s  = sStart + t9 + j;
            const bool vs = (s >= 0) && (s < DIM_D);

            // ---- stage 1: 9-wide W sums on sR[cur] (160 producers) ----
            if (vs && tid < 160) {
                const int r  = tid >> 2;
                const int g  = tid & 3;
                const int c0 = g << 2;
                const float* rIp = &sR[cur][0][r * RWDS];
                const float* rTp = &sR[cur][1][r * RWDS];
                const float4 ia  = *(const float4*)(rIp + c0);
                const float4 ib4 = *(const float4*)(rIp + c0 + 4);
                const float4 ic4 = *(const float4*)(rIp + c0 + 8);
                const float4 ta  = *(const float4*)(rTp + c0);
                const float4 tb4 = *(const float4*)(rTp + c0 + 4);
                const float4 tc4 = *(const float4*)(rTp + c0 + 8);
                const float iv[12] = {ia.x, ia.y, ia.z, ia.w, ib4.x, ib4.y, ib4.z, ib4.w,
                                      ic4.x, ic4.y, ic4.z, ic4.w};
                const float tv[12] = {ta.x, ta.y, ta.z, ta.w, tb4.x, tb4.y, tb4.z, tb4.w,
                                      tc4.x, tc4.y, tc4.z, tc4.w};
                float aI = 0.f, aT = 0.f, aII = 0.f, aTT = 0.f, aIT = 0.f;
#pragma unroll
                for (int k = 0; k < 9; ++k) {
                    aI += iv[k]; aT += tv[k];
                    aII = fmaf(iv[k], iv[k], aII);
                    aTT = fmaf(tv[k], tv[k], aTT);
                    aIT = fmaf(iv[k], tv[k], aIT);
                }
                wA[r][(c0 + r) & 15] = make_uint2(pkf16(aI, aT), pkf16(aII, aTT));
                wB[c0][r] = aIT;
#pragma unroll
                for (int q = 1; q < 4; ++q) {
                    const float ni = iv[8 + q], oi = iv[q - 1];
                    const float nt = tv[8 + q], ot = tv[q - 1];
                    aI += ni - oi; aT += nt - ot;
                    aII = fmaf(ni, ni, fmaf(oi, -oi, aII));
                    aTT = fmaf(nt, nt, fmaf(ot, -ot, aTT));
                    aIT = fmaf(ni, nt, fmaf(oi, -ot, aIT));
                    wA[r][(c0 + q + r) & 15] = make_uint2(pkf16(aI, aT), pkf16(aII, aTT));
                    wB[c0 + q][r] = aIT;
                }
            }
            asm volatile("s_waitcnt lgkmcnt(0)" ::: "memory");
            __builtin_amdgcn_s_barrier();   // wA/wB published; sR[cur] reads done

            // ---- issue glds for slice s+2 into sR[cur] (safe: readers done) ----
            issue(clampD(s + 2), cur);

            // ---- stage 2: 9-tall H sums (2 px) in packed f16 ----
            h2 SA, SB, PA, PB;
            float IT0, IT1;
            if (vs) {
                const uint2 C0 = wA[hb][(wo + hb) & 15];
                const h2 A0a = __builtin_bit_cast(h2, C0.x);
                const h2 A0b = __builtin_bit_cast(h2, C0.y);
                SA = A0a; SB = A0b;
#pragma unroll
                for (int k = 1; k < 9; ++k) {
                    const uint2 Ck = wA[hb + k][(wo + hb + k) & 15];
                    SA += __builtin_bit_cast(h2, Ck.x);
                    SB += __builtin_bit_cast(h2, Ck.y);
                }
                const uint2 C9 = wA[hb + 9][(wo + hb + 9) & 15];
                PA = SA - A0a + __builtin_bit_cast(h2, C9.x);
                PB = SB - A0b + __builtin_bit_cast(h2, C9.y);
                const float2 B0 = *(const float2*)&wB[wo][hb];
                const float2 B1 = *(const float2*)&wB[wo][hb + 2];
                const float2 B2 = *(const float2*)&wB[wo][hb + 4];
                const float2 B3 = *(const float2*)&wB[wo][hb + 6];
                const float2 B4 = *(const float2*)&wB[wo][hb + 8];
                IT0 = B0.x + B0.y + B1.x + B1.y + B2.x + B2.y + B3.x + B3.y + B4.x;
                IT1 = IT0 - B0.x + B4.y;
            } else {
                SA = HZ; SB = HZ; PA = HZ; PB = HZ; IT0 = 0.f; IT1 = 0.f;
            }

            // ---- D-rings (static slot j); running sums stay f32-exact:
            // add (float)new, subtract (float)same-bits-later -> no drift ----
            rnI[0]  += (float)SA.x - (float)rgA[0][j].x;
            rnT[0]  += (float)SA.y - (float)rgA[0][j].y;
            rnII[0] += (float)SB.x - (float)rgB[0][j].x;
            rnTT[0] += (float)SB.y - (float)rgB[0][j].y;
            rnIT[0] += IT0 - rgC[0][j];
            rgA[0][j] = SA; rgB[0][j] = SB; rgC[0][j] = IT0;
            rnI[1]  += (float)PA.x - (float)rgA[1][j].x;
            rnT[1]  += (float)PA.y - (float)rgA[1][j].y;
            rnII[1] += (float)PB.x - (float)rgB[1][j].x;
            rnTT[1] += (float)PB.y - (float)rgB[1][j].y;
            rnIT[1] += IT1 - rgC[1][j];
            rgA[1][j] = PA; rgB[1][j] = PB; rgC[1][j] = IT1;

            if ((s >= d0 + 4) && ((s - 4) < dEnd)) {
                float cr, vv, tvv;
                cr  = rnIT[0] - rnI[0] * rnT[0] * INV_K;
                vv  = rnII[0] - rnI[0] * rnI[0] * INV_K;
                tvv = rnTT[0] - rnT[0] * rnT[0] * INV_K;
                acc += cr * cr * __builtin_amdgcn_rcpf(fmaf(tvv, vv, 1e-5f));
                cr  = rnIT[1] - rnI[1] * rnT[1] * INV_K;
                vv  = rnII[1] - rnI[1] * rnI[1] * INV_K;
                tvv = rnTT[1] - rnT[1] * rnT[1] * INV_K;
                acc += cr * cr * __builtin_amdgcn_rcpf(fmaf(tvv, vv, 1e-5f));
            }

            // ---- certify own glds for slice s+1 landed (s+2's stay in flight) ----
            asm volatile("s_waitcnt lgkmcnt(0)" ::: "memory");
            asm volatile("s_waitcnt vmcnt(2)" ::: "memory");
            __builtin_amdgcn_s_barrier();
            cur ^= 1;
        }
    }

    // drain in-flight glds before reduction/exit
    asm volatile("s_waitcnt vmcnt(0)" ::: "memory");

    // ---- block reduction ----
#pragma unroll
    for (int off = 32; off > 0; off >>= 1) acc += __shfl_down(acc, off, 64);
    if (lane == 0) red[wid] = acc;
    __syncthreads();
    if (tid == 0) {
        const float bs = red[0] + red[1] + red[2] + red[3];
        atomicAdd(out, bs * (float)(-1.0 / NTOT));
    }
}

extern "C" void kernel_launch(void* const* d_in, const int* in_sizes, int n_in,
                              void* d_out, int out_size, void* d_ws, size_t ws_size,
                              hipStream_t stream) {
    const float* I = (const float*)d_in[0];
    const float* T = (const float*)d_in[1];
    float* out = (float*)d_out;
    float* ws  = (float*)d_ws;

    init_kernel<<<dim3(1), dim3(1), 0, stream>>>(out, ws);

    dim3 grid(DIM_W / TW, DIM_H / TH, DIM_B * NCH); // 10 x 6 x 18 = 1080
    dim3 block(256);
    lncc3d_kernel<<<grid, block, 0, stream>>>(I, T, ws, out);
}

// Round 16
// 85.469 us; speedup vs baseline: 2.2027x; 2.2027x over previous
//
#include <hip/hip_runtime.h>

#define DIM_W 160
#define DIM_H 192
#define DIM_D 160
#define DIM_B 2

constexpr int TW = 16;      // output tile width
constexpr int TH = 64;      // output tile height (P=2 px/thread, 512 threads)
constexpr int CH = 19;      // depth outputs per chunk (27 slices = 3 x 9)
constexpr int NCH = 9;      // ceil(160/19)
constexpr int RH = 72;      // region rows (TH + 8)
constexpr int RWDS = 24;    // words per region row (4 + 16 + 4 halo)
constexpr int RPAD = 1792;  // region words per field (72*24 = 1728, pad to 7 chunks)
constexpr float INV_K = 1.0f / 729.0f;
constexpr double NTOT = 9830400.0;

typedef unsigned int u32;
typedef __attribute__((address_space(1))) const u32 gu32;
typedef __attribute__((address_space(3))) u32 lu32;
typedef _Float16 h2 __attribute__((ext_vector_type(2)));

__global__ void init_kernel(float* out, float* ws) {
    out[0] = 0.0f;
    ws[0] = 0.0f; ws[1] = 0.0f; ws[2] = 0.0f; ws[3] = 0.0f;
}

__device__ __forceinline__ int clampD(int s) {
    return s < 0 ? 0 : (s > DIM_D - 1 ? DIM_D - 1 : s);
}

__device__ __forceinline__ u32 pkf16(float a, float b) {
    return __builtin_bit_cast(u32, __builtin_amdgcn_cvt_pkrtz(a, b));
}

__global__ __launch_bounds__(512)
void lncc3d_kernel(const float* __restrict__ I,
                   const float* __restrict__ T,
                   const float* __restrict__ zsrc,
                   float* __restrict__ out)
{
    // slice region: [buf][field][1792 words] = 72 rows x 24 words + glds pad.
    // Stage-1 phase (4r x 4g) hits quad (6r+g+c) mod 8 exactly twice = free.
    __shared__ __align__(16) float sR[2][2][RPAD];
    // W-sums f16-packed {pk(I,T),pk(II,TT)}: 8B cells, col rotated (c+r)&15
    __shared__ __align__(16) uint2 wA[RH][16];
    // W-sums IT f32, transposed [w][row], stride 74 (f2 reads cover all 32 banks)
    __shared__ __align__(16) float wB[16][74];
    __shared__ float red[8];

    const int tid  = threadIdx.x;
    const int lane = tid & 63;
    const int wid  = tid >> 6;            // 0..7
    const int wo   = tid & 15;
    const int hb   = (tid >> 4) << 1;     // 0,2,...,62

    const int bw = blockIdx.x, bh = blockIdx.y, bz = blockIdx.z;
    const int b  = bz / NCH;
    const int c  = bz - b * NCH;
    const int w0 = bw * TW, h0 = bh * TH, d0 = c * CH;
    const int dEnd = min(d0 + CH, DIM_D);

    const int plane = DIM_H * DIM_W;
    const float* Ib = I + (size_t)b * DIM_D * plane;
    const float* Tb = T + (size_t)b * DIM_D * plane;

    // glds: 14 jobs (2 fields x 7 chunks of 64x16B); wave w takes {w, w+8}
    const int njobs = (wid < 6) ? 2 : 1;
    int jfld[2], boff[2], ldof[2];
#pragma unroll
    for (int i = 0; i < 2; ++i) {
        const int job = wid + 8 * i;          // 0..13 (i<njobs)
        const int fld = job / 7;
        const int sub = job - fld * 7;
        const int s16 = sub * 64 + lane;
        const int row = s16 / 6;
        const int q   = s16 - row * 6;
        const int gh  = h0 - 4 + row;
        const int gw  = w0 - 4 + (q << 2);
        jfld[i] = fld;
        ldof[i] = sub << 8;                    // words within field
        boff[i] = (row < RH && gh >= 0 && gh < DIM_H && gw >= 0 && gw <= DIM_W - 4)
                  ? (gh * DIM_W + gw) : -1;
    }

    auto issue = [&](int sc, int buf) {
#pragma unroll
        for (int i = 0; i < 2; ++i) {
            if (i < njobs) {
                const float* Fs = (jfld[i] ? Tb : Ib) + (size_t)sc * plane;
                const float* gp = (boff[i] >= 0) ? (Fs + boff[i]) : zsrc;
                __builtin_amdgcn_global_load_lds((gu32*)gp,
                    (lu32*)&sR[buf][jfld[i]][ldof[i]], 16, 0, 0);
            }
        }
    };

    // D-rings (slot = static J) + running sums, 5 fields x 2 px (f32)
    float rgI[2][9], rgT[2][9], rgII[2][9], rgTT[2][9], rgIT[2][9];
    float rnI[2], rnT[2], rnII[2], rnTT[2], rnIT[2];
#pragma unroll
    for (int p = 0; p < 2; ++p) {
        rnI[p] = rnT[p] = rnII[p] = rnTT[p] = rnIT[p] = 0.0f;
#pragma unroll
        for (int q = 0; q < 9; ++q) {
            rgI[p][q] = rgT[p][q] = rgII[p][q] = rgTT[p][q] = rgIT[p][q] = 0.0f;
        }
    }
    float acc = 0.0f;

    const int sStart = d0 - 4;
    int cur = 0;

    // ---- prologue: stage sStart -> buf0, sStart+1 -> buf1 ----
    issue(clampD(sStart), 0);
    issue(clampD(sStart + 1), 1);
    if (wid < 6) { asm volatile("s_waitcnt vmcnt(2)" ::: "memory"); }
    else         { asm volatile("s_waitcnt vmcnt(1)" ::: "memory"); }
    __builtin_amdgcn_s_barrier();

    for (int t = 0; t < 3; ++t) {
        const int t9 = t * 9;
#pragma unroll
        for (int j = 0; j < 9; ++j) {
            const int s  = sStart + t9 + j;
            const bool vs = (s >= 0) && (s < DIM_D);

            // ---- stage 1: 9-wide W sums on sR[cur] (288 producers) ----
            if (vs && tid < 288) {
                const int r  = tid >> 2;      // 0..71
                const int g  = tid & 3;
                const int c0 = g << 2;
                const float* rIp = &sR[cur][0][r * RWDS];
                const float* rTp = &sR[cur][1][r * RWDS];
                const float4 ia  = *(const float4*)(rIp + c0);
                const float4 ib4 = *(const float4*)(rIp + c0 + 4);
                const float4 ic4 = *(const float4*)(rIp + c0 + 8);
                const float4 ta  = *(const float4*)(rTp + c0);
                const float4 tb4 = *(const float4*)(rTp + c0 + 4);
                const float4 tc4 = *(const float4*)(rTp + c0 + 8);
                const float iv[12] = {ia.x, ia.y, ia.z, ia.w, ib4.x, ib4.y, ib4.z, ib4.w,
                                      ic4.x, ic4.y, ic4.z, ic4.w};
                const float tv[12] = {ta.x, ta.y, ta.z, ta.w, tb4.x, tb4.y, tb4.z, tb4.w,
                                      tc4.x, tc4.y, tc4.z, tc4.w};
                float aI = 0.f, aT = 0.f, aII = 0.f, aTT = 0.f, aIT = 0.f;
#pragma unroll
                for (int k = 0; k < 9; ++k) {
                    aI += iv[k]; aT += tv[k];
                    aII = fmaf(iv[k], iv[k], aII);
                    aTT = fmaf(tv[k], tv[k], aTT);
                    aIT = fmaf(iv[k], tv[k], aIT);
                }
                wA[r][(c0 + r) & 15] = make_uint2(pkf16(aI, aT), pkf16(aII, aTT));
                wB[c0][r] = aIT;
#pragma unroll
                for (int q = 1; q < 4; ++q) {
                    const float ni = iv[8 + q], oi = iv[q - 1];
                    const float nt = tv[8 + q], ot = tv[q - 1];
                    aI += ni - oi; aT += nt - ot;
                    aII = fmaf(ni, ni, fmaf(oi, -oi, aII));
                    aTT = fmaf(nt, nt, fmaf(ot, -ot, aTT));
                    aIT = fmaf(ni, nt, fmaf(oi, -ot, aIT));
                    wA[r][(c0 + q + r) & 15] = make_uint2(pkf16(aI, aT), pkf16(aII, aTT));
                    wB[c0 + q][r] = aIT;
                }
            }
            asm volatile("s_waitcnt lgkmcnt(0)" ::: "memory");
            __builtin_amdgcn_s_barrier();   // wA/wB published; sR[cur] reads done

            // ---- issue glds for slice s+2 into sR[cur] (safe: readers done) ----
            issue(clampD(s + 2), cur);

            // ---- stage 2: 9-tall H sums (2 px) in packed f16 ----
            float s2I0, s2T0, s2II0, s2TT0, s2IT0, s2I1, s2T1, s2II1, s2TT1, s2IT1;
            if (vs) {
                const uint2 C0 = wA[hb][(wo + hb) & 15];
                const h2 A0a = __builtin_bit_cast(h2, C0.x);
                const h2 A0b = __builtin_bit_cast(h2, C0.y);
                h2 SA = A0a, SB = A0b;
#pragma unroll
                for (int k = 1; k < 9; ++k) {
                    const uint2 Ck = wA[hb + k][(wo + hb + k) & 15];
                    SA += __builtin_bit_cast(h2, Ck.x);
                    SB += __builtin_bit_cast(h2, Ck.y);
                }
                const uint2 C9 = wA[hb + 9][(wo + hb + 9) & 15];
                const h2 P1A = SA - A0a + __builtin_bit_cast(h2, C9.x);
                const h2 P1B = SB - A0b + __builtin_bit_cast(h2, C9.y);
                s2I0  = (float)SA.x;  s2T0  = (float)SA.y;
                s2II0 = (float)SB.x;  s2TT0 = (float)SB.y;
                s2I1  = (float)P1A.x; s2T1  = (float)P1A.y;
                s2II1 = (float)P1B.x; s2TT1 = (float)P1B.y;
                const float2 B0 = *(const float2*)&wB[wo][hb];
                const float2 B1 = *(const float2*)&wB[wo][hb + 2];
                const float2 B2 = *(const float2*)&wB[wo][hb + 4];
                const float2 B3 = *(const float2*)&wB[wo][hb + 6];
                const float2 B4 = *(const float2*)&wB[wo][hb + 8];
                s2IT0 = B0.x + B0.y + B1.x + B1.y + B2.x + B2.y
                      + B3.x + B3.y + B4.x;
                s2IT1 = s2IT0 - B0.x + B4.y;
            } else {
                s2I0 = s2T0 = s2II0 = s2TT0 = s2IT0 = 0.f;
                s2I1 = s2T1 = s2II1 = s2TT1 = s2IT1 = 0.f;
            }

            rnI[0]  += s2I0  - rgI[0][j];  rgI[0][j]  = s2I0;
            rnT[0]  += s2T0  - rgT[0][j];  rgT[0][j]  = s2T0;
            rnII[0] += s2II0 - rgII[0][j]; rgII[0][j] = s2II0;
            rnTT[0] += s2TT0 - rgTT[0][j]; rgTT[0][j] = s2TT0;
            rnIT[0] += s2IT0 - rgIT[0][j]; rgIT[0][j] = s2IT0;
            rnI[1]  += s2I1  - rgI[1][j];  rgI[1][j]  = s2I1;
            rnT[1]  += s2T1  - rgT[1][j];  rgT[1][j]  = s2T1;
            rnII[1] += s2II1 - rgII[1][j]; rgII[1][j] = s2II1;
            rnTT[1] += s2TT1 - rgTT[1][j]; rgTT[1][j] = s2TT1;
            rnIT[1] += s2IT1 - rgIT[1][j]; rgIT[1][j] = s2IT1;

            if ((s >= d0 + 4) && ((s - 4) < dEnd)) {
                float cr, vv, tvv;
                cr  = rnIT[0] - rnI[0] * rnT[0] * INV_K;
                vv  = rnII[0] - rnI[0] * rnI[0] * INV_K;
                tvv = rnTT[0] - rnT[0] * rnT[0] * INV_K;
                acc += cr * cr * __builtin_amdgcn_rcpf(fmaf(tvv, vv, 1e-5f));
                cr  = rnIT[1] - rnI[1] * rnT[1] * INV_K;
                vv  = rnII[1] - rnI[1] * rnI[1] * INV_K;
                tvv = rnTT[1] - rnT[1] * rnT[1] * INV_K;
                acc += cr * cr * __builtin_amdgcn_rcpf(fmaf(tvv, vv, 1e-5f));
            }

            // ---- certify own glds for slice s+1 landed (s+2's stay in flight) ----
            asm volatile("s_waitcnt lgkmcnt(0)" ::: "memory");
            if (wid < 6) { asm volatile("s_waitcnt vmcnt(2)" ::: "memory"); }
            else         { asm volatile("s_waitcnt vmcnt(1)" ::: "memory"); }
            __builtin_amdgcn_s_barrier();
            cur ^= 1;
        }
    }

    // drain in-flight glds before reduction/exit
    asm volatile("s_waitcnt vmcnt(0)" ::: "memory");

    // ---- block reduction (8 waves) ----
#pragma unroll
    for (int off = 32; off > 0; off >>= 1) acc += __shfl_down(acc, off, 64);
    if (lane == 0) red[wid] = acc;
    __syncthreads();
    if (tid == 0) {
        float bs = 0.0f;
#pragma unroll
        for (int k = 0; k < 8; ++k) bs += red[k];
        atomicAdd(out, bs * (float)(-1.0 / NTOT));
    }
}

extern "C" void kernel_launch(void* const* d_in, const int* in_sizes, int n_in,
                              void* d_out, int out_size, void* d_ws, size_t ws_size,
                              hipStream_t stream) {
    const float* I = (const float*)d_in[0];
    const float* T = (const float*)d_in[1];
    float* out = (float*)d_out;
    float* ws  = (float*)d_ws;

    init_kernel<<<dim3(1), dim3(1), 0, stream>>>(out, ws);

    dim3 grid(DIM_W / TW, DIM_H / TH, DIM_B * NCH); // 10 x 3 x 18 = 540
    dim3 block(512);
    lncc3d_kernel<<<grid, block, 0, stream>>>(I, T, ws, out);
}